// Round 11
// baseline (664.243 us; speedup 1.0000x reference)
//
#include <hip/hip_runtime.h>

#define HD 128
#define NEG 0.2f
#define BNEPS 1e-5f

typedef unsigned int uint32;
typedef __attribute__((ext_vector_type(8))) short short8;   // 8 bf16 (4 VGPRs)
typedef __attribute__((ext_vector_type(4))) float floatx4;  // MFMA acc

// ---------------- wave helpers ----------------

__device__ inline float wave_sum_f(float v) {
#pragma unroll
  for (int off = 32; off; off >>= 1) v += __shfl_xor(v, off, 64);
  return v;
}
__device__ inline int wave_iscan_i(int v, int lane) {
#pragma unroll
  for (int off = 1; off < 64; off <<= 1) {
    int t = __shfl_up(v, off, 64);
    if (lane >= off) v += t;
  }
  return v;
}
__device__ inline uint32 f2bf(float f) {  // fp32 -> bf16 (RNE), low 16 bits
  uint32 u = __float_as_uint(f);
  return (u + 0x7fffu + ((u >> 16) & 1u)) >> 16;
}
__device__ inline void kpair(int kc, int lg, int e2, bool perm, int& k_lo, int& k_hi) {
  if (!perm) {
    k_lo = kc * 32 + lg * 8 + e2 * 2;
    k_hi = k_lo + 1;
  } else {
    int w = kc * 16 + lg * 4 + e2;
    k_lo = ((w >> 4) << 5) + (w & 15);
    k_hi = k_lo + 16;
  }
}

// ---------------- combined pack + zero (deg, pooled, gcnt) ----------------
__global__ __launch_bounds__(256)
void k_pack(const float* __restrict__ W1, const float* __restrict__ as1v,
            const float* __restrict__ ad1v, const float* __restrict__ W2,
            const float* __restrict__ as2v, const float* __restrict__ ad2v,
            const float* __restrict__ W3, const float* __restrict__ as3v,
            const float* __restrict__ ad3v,
            const float* __restrict__ b1, const float* __restrict__ g1,
            const float* __restrict__ be1, const float* __restrict__ m1,
            const float* __restrict__ v1,
            const float* __restrict__ b2, const float* __restrict__ g2,
            const float* __restrict__ be2, const float* __restrict__ m2,
            const float* __restrict__ v2,
            const float* __restrict__ b3, const float* __restrict__ g3,
            const float* __restrict__ be3, const float* __restrict__ m3,
            const float* __restrict__ v3,
            uint32* __restrict__ PW1, uint32* __restrict__ PW2,
            uint32* __restrict__ PW3, uint32* __restrict__ BFA1,
            uint32* __restrict__ BFA2, uint32* __restrict__ BFA3,
            float4* __restrict__ BNAB, int* __restrict__ deg,
            int* __restrict__ gcnt, float* __restrict__ pooled, int G, int n) {
  const int b = blockIdx.x, t = threadIdx.x;
  if (b >= 83) {
    const int i = (b - 83) * 256 + t;
    if (i < n) deg[i] = 0;
    else if (i < n + G * HD) pooled[i - n] = 0.f;
    if (b == 83 && t == 0) gcnt[0] = 0;
    return;
  }
  if (b < 80) {
    const float* W;
    uint32* PW;
    int KC, local;
    bool perm;
    if (b < 16) { W = W1; PW = PW1; KC = 2; perm = false; local = b; }
    else if (b < 48) { W = W2; PW = PW2; KC = 4; perm = true; local = b - 16; }
    else { W = W3; PW = PW3; KC = 4; perm = true; local = b - 48; }
    const int idx = local * 256 + t;
    const int e2 = idx & 3, l = (idx >> 2) & 63, f = idx >> 8;
    const int kc = f % KC, ct = f / KC;
    int k_lo, k_hi;
    kpair(kc, l >> 4, e2, perm, k_lo, k_hi);
    const int col = ct * 16 + (l & 15);
    PW[idx] = f2bf(W[k_lo * HD + col]) | (f2bf(W[k_hi * HD + col]) << 16);
  } else {
    const int layer = b - 80;
    const float* W = layer == 0 ? W1 : layer == 1 ? W2 : W3;
    const float* av = layer == 0 ? as1v : layer == 1 ? as2v : as3v;
    const float* dv = layer == 0 ? ad1v : layer == 1 ? ad2v : ad3v;
    const float* bb = layer == 0 ? b1 : layer == 1 ? b2 : b3;
    const float* gg = layer == 0 ? g1 : layer == 1 ? g2 : g3;
    const float* bt = layer == 0 ? be1 : layer == 1 ? be2 : be3;
    const float* mm = layer == 0 ? m1 : layer == 1 ? m2 : m3;
    const float* vv = layer == 0 ? v1 : layer == 1 ? v2 : v3;
    uint32* BFA = layer == 0 ? BFA1 : layer == 1 ? BFA2 : BFA3;
    const int K = layer == 0 ? 64 : 128, KC = K / 32;
    const bool perm = layer != 0;
    __shared__ float ws[128], wd[128];
    if (t < K) {
      float s = 0.f, d = 0.f;
      for (int j = 0; j < HD; ++j) {
        const float w = W[t * HD + j];
        s = fmaf(w, av[j], s);
        d = fmaf(w, dv[j], d);
      }
      ws[t] = s;
      wd[t] = d;
    }
    __syncthreads();
    const int total = KC * 256;
    for (int idx = t; idx < total; idx += 256) {
      const int e2 = idx & 3, l = (idx >> 2) & 63, kc = idx >> 8;
      int k_lo, k_hi;
      kpair(kc, l >> 4, e2, perm, k_lo, k_hi);
      const int li = l & 15;
      const float lo = li == 0 ? ws[k_lo] : li == 1 ? wd[k_lo] : 0.f;
      const float hi = li == 0 ? ws[k_hi] : li == 1 ? wd[k_hi] : 0.f;
      BFA[idx] = f2bf(lo) | (f2bf(hi) << 16);
    }
    // BN fold: A = gam*rsqrt(var+eps); B = (bias - mu)*A + beta.
    if (t < 64) {
      const int c0 = (t >> 4) * 32 + (t & 15);
      const int c1 = c0 + 16;
      const float A0 = gg[c0] * rsqrtf(vv[c0] + BNEPS);
      const float A1 = gg[c1] * rsqrtf(vv[c1] + BNEPS);
      float4 r;
      r.x = A0;
      r.y = (bb[c0] - mm[c0]) * A0 + bt[c0];
      r.z = A1;
      r.w = (bb[c1] - mm[c1]) * A1 + bt[c1];
      BNAB[layer * 64 + t] = r;
    }
  }
}

// ---------------- CSR: atomic segment allocation (scan-free) ----------------
__global__ __launch_bounds__(256)
void k_alloc(const int* __restrict__ deg, int* __restrict__ gcnt,
             int2* __restrict__ offs2, int* __restrict__ csr,
             int* __restrict__ cursor, int n) {
  const int t = threadIdx.x, lane = t & 63, wave = t >> 6;
  const int i = blockIdx.x * 256 + t;
  const int v = (i < n) ? deg[i] + 1 : 0;  // +1 self-loop
  const int x = wave_iscan_i(v, lane);
  __shared__ int wsum[4];
  __shared__ int bbase;
  if (lane == 63) wsum[wave] = x;
  __syncthreads();
  if (t == 0) bbase = atomicAdd(gcnt, wsum[0] + wsum[1] + wsum[2] + wsum[3]);
  __syncthreads();
  int add = bbase;
#pragma unroll
  for (int w = 0; w < 4; ++w)
    if (w < wave) add += wsum[w];
  const int start = add + x - v;
  if (i < n) {
    csr[start] = i;  // self-loop first
    cursor[i] = start + 1;
    offs2[i] = make_int2(start, start + v);
  }
}

__global__ void k_fill_edges(const int* __restrict__ src, const int* __restrict__ dst,
                             int* __restrict__ cursor, int* __restrict__ csr, int E) {
  int i = blockIdx.x * blockDim.x + threadIdx.x;
  if (i < E) { int p = atomicAdd(&cursor[dst[i]], 1); csr[p] = src[i]; }
}

// ---------------- MFMA GEMM body ----------------
// h written to SLICE layout: SHh[k][node][8 words], k = word>>3 (8 slices of
// 1.6 MB -- each fits one XCD's L2 for the slice-gather kernel).
template <int K, bool BF16IN>
__device__ inline void gemm_body(int bid, const void* __restrict__ Xv,
                                 const uint32* __restrict__ PW,
                                 const uint32* __restrict__ BFA,
                                 uint32* __restrict__ SHh, float* __restrict__ ssrc,
                                 float* __restrict__ sdst, int n) {
  constexpr int KC = K / 32;
  __shared__ uint32 Xl[64 * K / 2];
  const int t = threadIdx.x;
  const int wv = t >> 6, l = t & 63;
  const int rowbase = bid * 64;

  short8 bfr[2][KC];
#pragma unroll
  for (int c2 = 0; c2 < 2; ++c2)
#pragma unroll
    for (int kc = 0; kc < KC; ++kc)
      bfr[c2][kc] = *((const short8*)PW + ((wv * 2 + c2) * KC + kc) * 64 + l);
  short8 bfa[KC];
  if (wv == 0) {
#pragma unroll
    for (int kc = 0; kc < KC; ++kc) bfa[kc] = *((const short8*)BFA + kc * 64 + l);
  }

  if (BF16IN) {
    const uint32* Xb = (const uint32*)Xv;
#pragma unroll
    for (int B = t; B < 64 * (K / 8); B += 256) {
      const int row = B / (K / 8), cb = B % (K / 8);
      const int r = min(rowbase + row, n - 1);
      const uint4 v = *(const uint4*)&Xb[(long)r * (K / 2) + cb * 4];
      *(uint4*)&Xl[row * (K / 2) + (cb ^ (row & 7)) * 4] = v;
    }
  } else {
    const float* X = (const float*)Xv;
    for (int i = t; i < 64 * (K / 4); i += 256) {
      const int row = i / (K / 4), kq = i % (K / 4);
      const int r = min(rowbase + row, n - 1);
      const float4 v = *(const float4*)&X[(long)r * K + kq * 4];
      uint2 p;
      p.x = f2bf(v.x) | (f2bf(v.y) << 16);
      p.y = f2bf(v.z) | (f2bf(v.w) << 16);
      int byte = row * (K * 2) + kq * 8;
      byte ^= (row & 7) << 4;
      *(uint2*)((char*)Xl + byte) = p;
    }
  }
  __syncthreads();

  floatx4 acc[4][2], acc2[4];
#pragma unroll
  for (int rt = 0; rt < 4; ++rt) {
    acc[rt][0] = (floatx4){0.f, 0.f, 0.f, 0.f};
    acc[rt][1] = (floatx4){0.f, 0.f, 0.f, 0.f};
    acc2[rt] = (floatx4){0.f, 0.f, 0.f, 0.f};
  }
  const int row_l = l & 15, kgrp = l >> 4;
#pragma unroll
  for (int rt = 0; rt < 4; ++rt) {
    const int row = rt * 16 + row_l;
#pragma unroll
    for (int kc = 0; kc < KC; ++kc) {
      const int byte = (row * (K * 2) + kc * 64 + kgrp * 16) ^ ((row & 7) << 4);
      const short8 af = *(const short8*)((const char*)Xl + byte);
      acc[rt][0] = __builtin_amdgcn_mfma_f32_16x16x32_bf16(af, bfr[0][kc], acc[rt][0], 0, 0, 0);
      acc[rt][1] = __builtin_amdgcn_mfma_f32_16x16x32_bf16(af, bfr[1][kc], acc[rt][1], 0, 0, 0);
      if (wv == 0)
        acc2[rt] = __builtin_amdgcn_mfma_f32_16x16x32_bf16(af, bfa[kc], acc2[rt], 0, 0, 0);
    }
  }

  // epilogue: packed bf16 h store to slice layout
  const int w = wv * 16 + row_l;             // logical word index 0..63
  const long slice_base = (long)(w >> 3) * n * 8 + (w & 7);
#pragma unroll
  for (int rt = 0; rt < 4; ++rt) {
#pragma unroll
    for (int r = 0; r < 4; ++r) {
      const int R = rowbase + rt * 16 + kgrp * 4 + r;
      if (R < n)
        SHh[slice_base + (long)R * 8] =
            f2bf(acc[rt][0][r]) | (f2bf(acc[rt][1][r]) << 16);
    }
  }
  if (wv == 0 && row_l < 2) {
    float* tgt = (row_l == 0) ? ssrc : sdst;
#pragma unroll
    for (int rt = 0; rt < 4; ++rt)
#pragma unroll
      for (int r = 0; r < 4; ++r) {
        const int R = rowbase + rt * 16 + kgrp * 4 + r;
        if (R < n) tgt[R] = acc2[rt][r];
      }
  }
}

__global__ __launch_bounds__(256)
void k_gemm1_hist(const void* __restrict__ Xv, const uint32* __restrict__ PW,
                  const uint32* __restrict__ BFA, uint32* __restrict__ SHh,
                  float* __restrict__ ssrc, float* __restrict__ sdst, int n,
                  const int* __restrict__ dst, int* __restrict__ deg, int E, int GB) {
  const int b = blockIdx.x;
  if (b < GB) {
    gemm_body<64, false>(b, Xv, PW, BFA, SHh, ssrc, sdst, n);
  } else {
    const int i = (b - GB) * 256 + threadIdx.x;
    if (i < E) atomicAdd(&deg[dst[i]], 1);
  }
}

template <int K>
__global__ __launch_bounds__(256)
void k_gemm_mfma(const void* __restrict__ Xv, const uint32* __restrict__ PW,
                 const uint32* __restrict__ BFA, uint32* __restrict__ SHh,
                 float* __restrict__ ssrc, float* __restrict__ sdst, int n) {
  gemm_body<K, true>(blockIdx.x, Xv, PW, BFA, SHh, ssrc, sdst, n);
}

// ---------------- coef: per-node softmax weights (matches reference's coef) ----------
// One wave per dst node. Gathers only the 200 KB ssrc table (L2-resident).
__global__ __launch_bounds__(256)
void k_coef(const float* __restrict__ ssrc, const float* __restrict__ sdst,
            const int2* __restrict__ offs2, const int* __restrict__ csr,
            float* __restrict__ coef, int n) {
  const int wid = (blockIdx.x * blockDim.x + threadIdx.x) >> 6;
  const int lane = threadIdx.x & 63;
  if (wid >= n) return;
  const int2 se = offs2[wid];
  const float sdv = sdst[wid];
  const int len = se.y - se.x;
  if (len <= 64) {  // common case (max degree ~45)
    float p = 0.f;
    if (lane < len) {
      const int s = csr[se.x + lane];
      const float tt = ssrc[s] + sdv;
      const float e = (tt > 0.f) ? tt : NEG * tt;
      p = __expf(e);
    }
    const float inv = 1.f / wave_sum_f(p);
    if (lane < len) coef[se.x + lane] = p * inv;
  } else {
    float denom = 0.f;
    for (int base = se.x; base < se.y; base += 64) {
      const int m = min(64, se.y - base);
      float p = 0.f;
      if (lane < m) {
        const int s = csr[base + lane];
        const float tt = ssrc[s] + sdv;
        const float e = (tt > 0.f) ? tt : NEG * tt;
        p = __expf(e);
      }
      denom += wave_sum_f(p);
    }
    const float inv = 1.f / denom;
    for (int base = se.x; base < se.y; base += 64) {
      const int m = min(64, se.y - base);
      if (lane < m) {
        const int s = csr[base + lane];
        const float tt = ssrc[s] + sdv;
        const float e = (tt > 0.f) ? tt : NEG * tt;
        coef[base + lane] = __expf(e) * inv;
      }
    }
  }
}

// ---------------- slice-gather: weighted sum over one column slice ----------------
// Block b: slice k = b%8 (-> XCD k under round-robin dispatch), nodes
// [(b>>3)*64, +64). Wave = 8 edge-groups x 8 word-lanes; per iter each group
// gathers 32 B from the 1.6 MB L2-resident slice table. csr/coef are
// sequential nontemporal streams. BN+ReLU fused; Ybf keeps the packed layout.
__global__ __launch_bounds__(256)
void k_slice(const uint32* __restrict__ SHh, const float* __restrict__ coef,
             const int2* __restrict__ offs2, const int* __restrict__ csr,
             const float4* __restrict__ BNAB, uint32* __restrict__ Ybf, int n) {
  const int k = blockIdx.x & 7;
  const int node0 = (blockIdx.x >> 3) * 64 + (threadIdx.x >> 6) * 16;
  const int lane = threadIdx.x & 63;
  const int eg = lane >> 3, wd = lane & 7;
  const uint32* T = SHh + (long)k * n * 8;
  const float4 ab = BNAB[k * 8 + wd];
  for (int u = 0; u < 16; ++u) {
    const int node = node0 + u;
    if (node >= n) return;
    const int2 se = offs2[node];
    float a0 = 0.f, a1 = 0.f;
    for (int j = se.x + eg; j < se.y; j += 8) {
      const int s = __builtin_nontemporal_load(&csr[j]);
      const float c = __builtin_nontemporal_load(&coef[j]);
      const uint32 g = T[(long)s * 8 + wd];
      a0 = fmaf(c, __uint_as_float(g << 16), a0);
      a1 = fmaf(c, __uint_as_float(g & 0xffff0000u), a1);
    }
    a0 += __shfl_xor(a0, 8, 64);
    a1 += __shfl_xor(a1, 8, 64);
    a0 += __shfl_xor(a0, 16, 64);
    a1 += __shfl_xor(a1, 16, 64);
    a0 += __shfl_xor(a0, 32, 64);
    a1 += __shfl_xor(a1, 32, 64);
    if (eg == 0) {
      const float v0 = fmaxf(fmaf(a0, ab.x, ab.y), 0.f);
      const float v1 = fmaxf(fmaf(a1, ab.z, ab.w), 0.f);
      __builtin_nontemporal_store(f2bf(v0) | (f2bf(v1) << 16),
                                  &Ybf[(long)node * 64 + k * 8 + wd]);
    }
  }
}

// ---------------- pool: 4 partial blocks per graph + atomic combine ----------------
__global__ __launch_bounds__(256)
void k_pool_part(const uint32* __restrict__ Ybf, const int* __restrict__ batch,
                 int n, float* __restrict__ pooled) {
  const int g = blockIdx.x >> 2, q = blockIdx.x & 3;
  const int wave = threadIdx.x >> 6, lane = threadIdx.x & 63;
  int lo = 0, hi = n;
  while (lo < hi) { int mid = (lo + hi) >> 1; if (batch[mid] < g) lo = mid + 1; else hi = mid; }
  const int start = lo;
  hi = n;
  while (lo < hi) { int mid = (lo + hi) >> 1; if (batch[mid] < g + 1) lo = mid + 1; else hi = mid; }
  const int len = lo - start;
  const int qs = start + (len * q) / 4;
  const int qe = start + (len * (q + 1)) / 4;
  const int c0 = (lane >> 4) * 32 + (lane & 15), c1 = c0 + 16;
  float m0 = 0.f, m1 = 0.f;
  for (int i = qs + wave; i < qe; i += 4) {
    const uint32 gv = Ybf[(long)i * 64 + lane];
    m0 += __uint_as_float(gv << 16);
    m1 += __uint_as_float(gv & 0xffff0000u);
  }
  __shared__ float red[4][HD];
  red[wave][c0] = m0;
  red[wave][c1] = m1;
  __syncthreads();
  if (wave == 0) {
    m0 = red[0][c0] + red[1][c0] + red[2][c0] + red[3][c0];
    m1 = red[0][c1] + red[1][c1] + red[2][c1] + red[3][c1];
    atomicAdd(&pooled[g * HD + c0], m0);
    atomicAdd(&pooled[g * HD + c1], m1);
  }
}

// ---------------- MLP head: one wave per graph (4 graphs per block) ----------------
__global__ __launch_bounds__(256)
void k_head(const float* __restrict__ pooled, const int* __restrict__ batch, int n,
            int G, const float* __restrict__ lw1, const float* __restrict__ lb1,
            const float* __restrict__ lw2, const float* __restrict__ lb2,
            float* __restrict__ out) {
  const int g = blockIdx.x * 4 + (threadIdx.x >> 6);
  const int lane = threadIdx.x & 63;
  if (g >= G) return;
  int lo = 0, hi = n;
  while (lo < hi) { int mid = (lo + hi) >> 1; if (batch[mid] < g) lo = mid + 1; else hi = mid; }
  const int start = lo;
  hi = n;
  while (lo < hi) { int mid = (lo + hi) >> 1; if (batch[mid] < g + 1) lo = mid + 1; else hi = mid; }
  const int cnt = lo - start;
  const float invc = (cnt > 0) ? 1.f / (float)cnt : 0.f;
  const int c0 = (lane >> 4) * 32 + (lane & 15), c1 = c0 + 16;
  const float m0 = pooled[g * HD + c0] * invc;
  const float m1 = pooled[g * HD + c1] * invc;
  float t0 = lb1[c0], t1 = lb1[c1];
  for (int k = 0; k < HD; ++k) {
    const int srcl = ((k >> 5) << 4) + (k & 15);
    const float pv = __shfl(((k >> 4) & 1) ? m1 : m0, srcl, 64);
    t0 = fmaf(pv, lw1[k * HD + c0], t0);
    t1 = fmaf(pv, lw1[k * HD + c1], t1);
  }
  t0 = fmaxf(t0, 0.f);
  t1 = fmaxf(t1, 0.f);
  float p = t0 * lw2[c0] + t1 * lw2[c1];
#pragma unroll
  for (int off = 32; off; off >>= 1) p += __shfl_xor(p, off, 64);
  if (lane == 0) out[g] = p + lb2[0];
}

// ---------------- launch ----------------

extern "C" void kernel_launch(void* const* d_in, const int* in_sizes, int n_in,
                              void* d_out, int out_size, void* d_ws, size_t ws_size,
                              hipStream_t stream) {
  const float* x = (const float*)d_in[0];
  const int* ei = (const int*)d_in[1];
  const int* batch = (const int*)d_in[2];
  const float* W1 = (const float*)d_in[3];
  const float* as1 = (const float*)d_in[4];
  const float* ad1 = (const float*)d_in[5];
  const float* b1 = (const float*)d_in[6];
  const float* W2 = (const float*)d_in[7];
  const float* as2 = (const float*)d_in[8];
  const float* ad2 = (const float*)d_in[9];
  const float* b2 = (const float*)d_in[10];
  const float* W3 = (const float*)d_in[11];
  const float* as3 = (const float*)d_in[12];
  const float* ad3 = (const float*)d_in[13];
  const float* b3 = (const float*)d_in[14];
  const float* g1 = (const float*)d_in[15];
  const float* be1 = (const float*)d_in[16];
  const float* m1 = (const float*)d_in[17];
  const float* v1 = (const float*)d_in[18];
  const float* g2 = (const float*)d_in[19];
  const float* be2 = (const float*)d_in[20];
  const float* m2 = (const float*)d_in[21];
  const float* v2 = (const float*)d_in[22];
  const float* g3 = (const float*)d_in[23];
  const float* be3 = (const float*)d_in[24];
  const float* m3 = (const float*)d_in[25];
  const float* v3 = (const float*)d_in[26];
  const float* lw1 = (const float*)d_in[27];
  const float* lb1 = (const float*)d_in[28];
  const float* lw2 = (const float*)d_in[29];
  const float* lb2 = (const float*)d_in[30];

  const int n = in_sizes[0] / 64;  // 50000
  const int E = in_sizes[1] / 2;   // 640000
  const int G = out_size;          // 256 graphs
  const int* src = ei;
  const int* dst = ei + E;

  // workspace carve (4B units)
  uint32* hbuf = (uint32*)d_ws;        // n*64 (bf16x2, slice layout)
  uint32* ybuf = hbuf + (long)n * 64;  // n*64 (bf16x2, packed layout)
  float* ssrc = (float*)(ybuf + (long)n * 64);  // n
  float* sdstv = ssrc + n;             // n
  int* deg = (int*)(sdstv + n);        // n
  int2* offs2 = (int2*)(deg + n);      // n int2
  int* cursor = (int*)(offs2 + n);     // n
  int* csr = cursor + n;               // E+n
  float* coef = (float*)(csr + (E + n));  // E+n
  int* gcnt = (int*)(coef + (E + n));  // 1 (+pad)
  uint32* PW1 = (uint32*)(gcnt + 4);   // 4096
  uint32* PW2 = PW1 + 4096;            // 8192
  uint32* PW3 = PW2 + 8192;            // 8192
  uint32* BFA1 = PW3 + 8192;           // 512
  uint32* BFA2 = BFA1 + 512;           // 1024
  uint32* BFA3 = BFA2 + 1024;          // 1024
  float4* BNAB = (float4*)(BFA3 + 1024);  // 3*64 float4
  float* pooled = (float*)(BNAB + 3 * 64);  // G*HD floats

  const int B = 256;
  dim3 blk(B);
  const int nb = (n + B - 1) / B;
  const int eb = (E + B - 1) / B;
  const int zb = (n + G * HD + B - 1) / B;  // zero deg + pooled
  const int GB = (n + 63) / 64;

  // 1: pack (PW + score fragments + BN fold) + zero deg/pooled/gcnt
  k_pack<<<dim3(83 + zb), blk, 0, stream>>>(
      W1, as1, ad1, W2, as2, ad2, W3, as3, ad3,
      b1, g1, be1, m1, v1, b2, g2, be2, m2, v2, b3, g3, be3, m3, v3,
      PW1, PW2, PW3, BFA1, BFA2, BFA3, BNAB, deg, gcnt, pooled, G, n);
  // 2: layer-1 gemm (fp32 in) || edge histogram
  k_gemm1_hist<<<dim3(GB + eb), blk, 0, stream>>>(x, PW1, BFA1, hbuf, ssrc, sdstv, n,
                                                  dst, deg, E, GB);
  // 3: CSR segment allocation (scan-free)
  k_alloc<<<dim3(nb), blk, 0, stream>>>(deg, gcnt, offs2, csr, cursor, n);
  // 4: CSR edge fill
  k_fill_edges<<<dim3(eb), blk, 0, stream>>>(src, dst, cursor, csr, E);

  const dim3 cgrid((n + 3) / 4);
  const dim3 sgrid(8 * GB);  // 8 slices x 64-node blocks
  // layer 1
  k_coef<<<cgrid, blk, 0, stream>>>(ssrc, sdstv, offs2, csr, coef, n);
  k_slice<<<sgrid, blk, 0, stream>>>(hbuf, coef, offs2, csr, BNAB + 0, ybuf, n);
  // layer 2
  k_gemm_mfma<128><<<dim3(GB), blk, 0, stream>>>(ybuf, PW2, BFA2, hbuf, ssrc, sdstv, n);
  k_coef<<<cgrid, blk, 0, stream>>>(ssrc, sdstv, offs2, csr, coef, n);
  k_slice<<<sgrid, blk, 0, stream>>>(hbuf, coef, offs2, csr, BNAB + 64, ybuf, n);
  // layer 3
  k_gemm_mfma<128><<<dim3(GB), blk, 0, stream>>>(ybuf, PW3, BFA3, hbuf, ssrc, sdstv, n);
  k_coef<<<cgrid, blk, 0, stream>>>(ssrc, sdstv, offs2, csr, coef, n);
  k_slice<<<sgrid, blk, 0, stream>>>(hbuf, coef, offs2, csr, BNAB + 128, ybuf, n);
  // pool partials (4 blocks/graph) + head
  k_pool_part<<<dim3(4 * G), blk, 0, stream>>>(ybuf, batch, n, pooled);
  k_head<<<dim3((G + 3) / 4), blk, 0, stream>>>(pooled, batch, n, G, lw1, lb1, lw2,
                                                lb2, (float*)d_out);
}

// Round 12
// 225.534 us; speedup vs baseline: 2.9452x; 2.9452x over previous
//
#include <hip/hip_runtime.h>

#define HD 128
#define NEG 0.2f
#define BNEPS 1e-5f

typedef unsigned int uint32;
typedef __attribute__((ext_vector_type(8))) short short8;   // 8 bf16 (4 VGPRs)
typedef __attribute__((ext_vector_type(4))) float floatx4;  // MFMA acc

// ---------------- wave helpers ----------------

__device__ inline float wave_sum_f(float v) {
#pragma unroll
  for (int off = 32; off; off >>= 1) v += __shfl_xor(v, off, 64);
  return v;
}
__device__ inline int wave_iscan_i(int v, int lane) {
#pragma unroll
  for (int off = 1; off < 64; off <<= 1) {
    int t = __shfl_up(v, off, 64);
    if (lane >= off) v += t;
  }
  return v;
}
__device__ inline uint32 f2bf(float f) {  // fp32 -> bf16 (RNE), low 16 bits
  uint32 u = __float_as_uint(f);
  return (u + 0x7fffu + ((u >> 16) & 1u)) >> 16;
}
__device__ inline void kpair(int kc, int lg, int e2, bool perm, int& k_lo, int& k_hi) {
  if (!perm) {
    k_lo = kc * 32 + lg * 8 + e2 * 2;
    k_hi = k_lo + 1;
  } else {
    int w = kc * 16 + lg * 4 + e2;
    k_lo = ((w >> 4) << 5) + (w & 15);
    k_hi = k_lo + 16;
  }
}

// ---------------- combined pack + zero (deg, pooled, gcnt) ----------------
__global__ __launch_bounds__(256)
void k_pack(const float* __restrict__ W1, const float* __restrict__ as1v,
            const float* __restrict__ ad1v, const float* __restrict__ W2,
            const float* __restrict__ as2v, const float* __restrict__ ad2v,
            const float* __restrict__ W3, const float* __restrict__ as3v,
            const float* __restrict__ ad3v,
            const float* __restrict__ b1, const float* __restrict__ g1,
            const float* __restrict__ be1, const float* __restrict__ m1,
            const float* __restrict__ v1,
            const float* __restrict__ b2, const float* __restrict__ g2,
            const float* __restrict__ be2, const float* __restrict__ m2,
            const float* __restrict__ v2,
            const float* __restrict__ b3, const float* __restrict__ g3,
            const float* __restrict__ be3, const float* __restrict__ m3,
            const float* __restrict__ v3,
            uint32* __restrict__ PW1, uint32* __restrict__ PW2,
            uint32* __restrict__ PW3, uint32* __restrict__ BFA1,
            uint32* __restrict__ BFA2, uint32* __restrict__ BFA3,
            float4* __restrict__ BNAB, int* __restrict__ deg,
            int* __restrict__ gcnt, float* __restrict__ pooled, int G, int n) {
  const int b = blockIdx.x, t = threadIdx.x;
  if (b >= 83) {
    const int i = (b - 83) * 256 + t;
    if (i < n) deg[i] = 0;
    else if (i < n + G * HD) pooled[i - n] = 0.f;
    if (b == 83 && t == 0) gcnt[0] = 0;
    return;
  }
  if (b < 80) {
    const float* W;
    uint32* PW;
    int KC, local;
    bool perm;
    if (b < 16) { W = W1; PW = PW1; KC = 2; perm = false; local = b; }
    else if (b < 48) { W = W2; PW = PW2; KC = 4; perm = true; local = b - 16; }
    else { W = W3; PW = PW3; KC = 4; perm = true; local = b - 48; }
    const int idx = local * 256 + t;
    const int e2 = idx & 3, l = (idx >> 2) & 63, f = idx >> 8;
    const int kc = f % KC, ct = f / KC;
    int k_lo, k_hi;
    kpair(kc, l >> 4, e2, perm, k_lo, k_hi);
    const int col = ct * 16 + (l & 15);
    PW[idx] = f2bf(W[k_lo * HD + col]) | (f2bf(W[k_hi * HD + col]) << 16);
  } else {
    const int layer = b - 80;
    const float* W = layer == 0 ? W1 : layer == 1 ? W2 : W3;
    const float* av = layer == 0 ? as1v : layer == 1 ? as2v : as3v;
    const float* dv = layer == 0 ? ad1v : layer == 1 ? ad2v : ad3v;
    const float* bb = layer == 0 ? b1 : layer == 1 ? b2 : b3;
    const float* gg = layer == 0 ? g1 : layer == 1 ? g2 : g3;
    const float* bt = layer == 0 ? be1 : layer == 1 ? be2 : be3;
    const float* mm = layer == 0 ? m1 : layer == 1 ? m2 : m3;
    const float* vv = layer == 0 ? v1 : layer == 1 ? v2 : v3;
    uint32* BFA = layer == 0 ? BFA1 : layer == 1 ? BFA2 : BFA3;
    const int K = layer == 0 ? 64 : 128, KC = K / 32;
    const bool perm = layer != 0;
    __shared__ float ws[128], wd[128];
    if (t < K) {
      float s = 0.f, d = 0.f;
      for (int j = 0; j < HD; ++j) {
        const float w = W[t * HD + j];
        s = fmaf(w, av[j], s);
        d = fmaf(w, dv[j], d);
      }
      ws[t] = s;
      wd[t] = d;
    }
    __syncthreads();
    const int total = KC * 256;
    for (int idx = t; idx < total; idx += 256) {
      const int e2 = idx & 3, l = (idx >> 2) & 63, kc = idx >> 8;
      int k_lo, k_hi;
      kpair(kc, l >> 4, e2, perm, k_lo, k_hi);
      const int li = l & 15;
      const float lo = li == 0 ? ws[k_lo] : li == 1 ? wd[k_lo] : 0.f;
      const float hi = li == 0 ? ws[k_hi] : li == 1 ? wd[k_hi] : 0.f;
      BFA[idx] = f2bf(lo) | (f2bf(hi) << 16);
    }
    // BN fold: A = gam*rsqrt(var+eps); B = (bias - mu)*A + beta.
    if (t < 64) {
      const int c0 = (t >> 4) * 32 + (t & 15);
      const int c1 = c0 + 16;
      const float A0 = gg[c0] * rsqrtf(vv[c0] + BNEPS);
      const float A1 = gg[c1] * rsqrtf(vv[c1] + BNEPS);
      float4 r;
      r.x = A0;
      r.y = (bb[c0] - mm[c0]) * A0 + bt[c0];
      r.z = A1;
      r.w = (bb[c1] - mm[c1]) * A1 + bt[c1];
      BNAB[layer * 64 + t] = r;
    }
  }
}

// ---------------- CSR: atomic segment allocation (scan-free, unbucketed) ----------------
__global__ __launch_bounds__(256)
void k_alloc(const int* __restrict__ deg, int* __restrict__ gcnt,
             int2* __restrict__ offs2, int* __restrict__ csr,
             int* __restrict__ cursor, int n) {
  const int t = threadIdx.x, lane = t & 63, wave = t >> 6;
  const int i = blockIdx.x * 256 + t;
  const int v = (i < n) ? deg[i] + 1 : 0;  // +1 self-loop
  const int x = wave_iscan_i(v, lane);
  __shared__ int wsum[4];
  __shared__ int bbase;
  if (lane == 63) wsum[wave] = x;
  __syncthreads();
  if (t == 0) bbase = atomicAdd(gcnt, wsum[0] + wsum[1] + wsum[2] + wsum[3]);
  __syncthreads();
  int add = bbase;
#pragma unroll
  for (int w = 0; w < 4; ++w)
    if (w < wave) add += wsum[w];
  const int start = add + x - v;
  if (i < n) {
    csr[start] = i;  // self-loop first
    cursor[i] = start + 1;
    offs2[i] = make_int2(start, start + v);
  }
}

__global__ void k_fill_edges(const int* __restrict__ src, const int* __restrict__ dst,
                             int* __restrict__ cursor, int* __restrict__ csr, int E) {
  int i = blockIdx.x * blockDim.x + threadIdx.x;
  if (i < E) { int p = atomicAdd(&cursor[dst[i]], 1); csr[p] = src[i]; }
}

// ---------------- MFMA GEMM body ----------------
template <int K, bool BF16IN>
__device__ inline void gemm_body(int bid, const void* __restrict__ Xv,
                                 const uint32* __restrict__ PW,
                                 const uint32* __restrict__ BFA,
                                 uint32* __restrict__ Hh, float* __restrict__ ssrc,
                                 float* __restrict__ sdst, int n) {
  constexpr int KC = K / 32;
  __shared__ uint32 Xl[64 * K / 2];
  const int t = threadIdx.x;
  const int wv = t >> 6, l = t & 63;
  const int rowbase = bid * 64;

  short8 bfr[2][KC];
#pragma unroll
  for (int c2 = 0; c2 < 2; ++c2)
#pragma unroll
    for (int kc = 0; kc < KC; ++kc)
      bfr[c2][kc] = *((const short8*)PW + ((wv * 2 + c2) * KC + kc) * 64 + l);
  short8 bfa[KC];
  if (wv == 0) {
#pragma unroll
    for (int kc = 0; kc < KC; ++kc) bfa[kc] = *((const short8*)BFA + kc * 64 + l);
  }

  if (BF16IN) {
    const uint32* Xb = (const uint32*)Xv;
#pragma unroll
    for (int B = t; B < 64 * (K / 8); B += 256) {
      const int row = B / (K / 8), cb = B % (K / 8);
      const int r = min(rowbase + row, n - 1);
      const uint4 v = *(const uint4*)&Xb[(long)r * (K / 2) + cb * 4];
      *(uint4*)&Xl[row * (K / 2) + (cb ^ (row & 7)) * 4] = v;
    }
  } else {
    const float* X = (const float*)Xv;
    for (int i = t; i < 64 * (K / 4); i += 256) {
      const int row = i / (K / 4), kq = i % (K / 4);
      const int r = min(rowbase + row, n - 1);
      const float4 v = *(const float4*)&X[(long)r * K + kq * 4];
      uint2 p;
      p.x = f2bf(v.x) | (f2bf(v.y) << 16);
      p.y = f2bf(v.z) | (f2bf(v.w) << 16);
      int byte = row * (K * 2) + kq * 8;
      byte ^= (row & 7) << 4;
      *(uint2*)((char*)Xl + byte) = p;
    }
  }
  __syncthreads();

  floatx4 acc[4][2], acc2[4];
#pragma unroll
  for (int rt = 0; rt < 4; ++rt) {
    acc[rt][0] = (floatx4){0.f, 0.f, 0.f, 0.f};
    acc[rt][1] = (floatx4){0.f, 0.f, 0.f, 0.f};
    acc2[rt] = (floatx4){0.f, 0.f, 0.f, 0.f};
  }
  const int row_l = l & 15, kgrp = l >> 4;
#pragma unroll
  for (int rt = 0; rt < 4; ++rt) {
    const int row = rt * 16 + row_l;
#pragma unroll
    for (int kc = 0; kc < KC; ++kc) {
      const int byte = (row * (K * 2) + kc * 64 + kgrp * 16) ^ ((row & 7) << 4);
      const short8 af = *(const short8*)((const char*)Xl + byte);
      acc[rt][0] = __builtin_amdgcn_mfma_f32_16x16x32_bf16(af, bfr[0][kc], acc[rt][0], 0, 0, 0);
      acc[rt][1] = __builtin_amdgcn_mfma_f32_16x16x32_bf16(af, bfr[1][kc], acc[rt][1], 0, 0, 0);
      if (wv == 0)
        acc2[rt] = __builtin_amdgcn_mfma_f32_16x16x32_bf16(af, bfa[kc], acc2[rt], 0, 0, 0);
    }
  }

#pragma unroll
  for (int rt = 0; rt < 4; ++rt) {
#pragma unroll
    for (int r = 0; r < 4; ++r) {
      const int R = rowbase + rt * 16 + kgrp * 4 + r;
      if (R < n)
        Hh[(long)R * 64 + wv * 16 + row_l] =
            f2bf(acc[rt][0][r]) | (f2bf(acc[rt][1][r]) << 16);
    }
  }
  if (wv == 0 && row_l < 2) {
    float* tgt = (row_l == 0) ? ssrc : sdst;
#pragma unroll
    for (int rt = 0; rt < 4; ++rt)
#pragma unroll
      for (int r = 0; r < 4; ++r) {
        const int R = rowbase + rt * 16 + kgrp * 4 + r;
        if (R < n) tgt[R] = acc2[rt][r];
      }
  }
}

__global__ __launch_bounds__(256)
void k_gemm1_hist(const void* __restrict__ Xv, const uint32* __restrict__ PW,
                  const uint32* __restrict__ BFA, uint32* __restrict__ Hh,
                  float* __restrict__ ssrc, float* __restrict__ sdst, int n,
                  const int* __restrict__ dst, int* __restrict__ deg, int E, int GB) {
  const int b = blockIdx.x;
  if (b < GB) {
    gemm_body<64, false>(b, Xv, PW, BFA, Hh, ssrc, sdst, n);
  } else {
    const int i = (b - GB) * 256 + threadIdx.x;
    if (i < E) atomicAdd(&deg[dst[i]], 1);
  }
}

template <int K>
__global__ __launch_bounds__(256)
void k_gemm_mfma(const void* __restrict__ Xv, const uint32* __restrict__ PW,
                 const uint32* __restrict__ BFA, uint32* __restrict__ Hh,
                 float* __restrict__ ssrc, float* __restrict__ sdst, int n) {
  gemm_body<K, true>(blockIdx.x, Xv, PW, BFA, Hh, ssrc, sdst, n);
}

// ---------------- per-dst-node softmax aggregation (R8-measured-best form) ----------
// One wave per dst node; 16-wide guarded gather batches; BN+bias folded (BNAB).
__global__ __launch_bounds__(256)
void k_agg(const uint32* __restrict__ Hh, const float* __restrict__ ssrc,
           const float* __restrict__ sdst, const int2* __restrict__ offs2,
           const int* __restrict__ csr, const float4* __restrict__ BNAB,
           uint32* __restrict__ Ybf, int n) {
  const int wid = (blockIdx.x * blockDim.x + threadIdx.x) >> 6;
  const int lane = threadIdx.x & 63;
  if (wid >= n) return;
  const int2 se = offs2[wid];
  const float sdv = sdst[wid];
  float acc0 = 0.f, acc1 = 0.f, denom = 0.f;
  for (int base = se.x; base < se.y; base += 64) {
    const int m = min(64, se.y - base);
    int sidx = 0;
    float p = 0.f;
    if (lane < m) {
      sidx = csr[base + lane];
      const float tt = ssrc[sidx] + sdv;
      const float e = (tt > 0.f) ? tt : NEG * tt;
      p = __expf(e);
    }
    denom += wave_sum_f(p);
    const uint32 pu = __float_as_uint(p);
    for (int jj = 0; jj < m; jj += 16) {
      uint32 g[16];
#pragma unroll
      for (int u = 0; u < 16; ++u) {
        if (jj + u < m) {
          const int s = __builtin_amdgcn_readlane(sidx, jj + u);
          g[u] = Hh[(long)s * 64 + lane];
        }
      }
#pragma unroll
      for (int u = 0; u < 16; ++u) {
        if (jj + u < m) {
          const float w = __uint_as_float(__builtin_amdgcn_readlane(pu, jj + u));
          acc0 = fmaf(w, __uint_as_float(g[u] << 16), acc0);
          acc1 = fmaf(w, __uint_as_float(g[u] & 0xffff0000u), acc1);
        }
      }
    }
  }
  const float inv = 1.f / denom;
  const float4 ab = BNAB[lane];
  const float v0 = fmaxf(fmaf(acc0 * inv, ab.x, ab.y), 0.f);
  const float v1 = fmaxf(fmaf(acc1 * inv, ab.z, ab.w), 0.f);
  Ybf[(long)wid * 64 + lane] = f2bf(v0) | (f2bf(v1) << 16);
}

// ---------------- pool: 4 partial blocks per graph + atomic combine ----------------
__global__ __launch_bounds__(256)
void k_pool_part(const uint32* __restrict__ Ybf, const int* __restrict__ batch,
                 int n, float* __restrict__ pooled) {
  const int g = blockIdx.x >> 2, q = blockIdx.x & 3;
  const int wave = threadIdx.x >> 6, lane = threadIdx.x & 63;
  int lo = 0, hi = n;
  while (lo < hi) { int mid = (lo + hi) >> 1; if (batch[mid] < g) lo = mid + 1; else hi = mid; }
  const int start = lo;
  hi = n;
  while (lo < hi) { int mid = (lo + hi) >> 1; if (batch[mid] < g + 1) lo = mid + 1; else hi = mid; }
  const int len = lo - start;
  const int qs = start + (len * q) / 4;
  const int qe = start + (len * (q + 1)) / 4;
  const int c0 = (lane >> 4) * 32 + (lane & 15), c1 = c0 + 16;
  float m0 = 0.f, m1 = 0.f;
  for (int i = qs + wave; i < qe; i += 4) {
    const uint32 gv = Ybf[(long)i * 64 + lane];
    m0 += __uint_as_float(gv << 16);
    m1 += __uint_as_float(gv & 0xffff0000u);
  }
  __shared__ float red[4][HD];
  red[wave][c0] = m0;
  red[wave][c1] = m1;
  __syncthreads();
  if (wave == 0) {
    m0 = red[0][c0] + red[1][c0] + red[2][c0] + red[3][c0];
    m1 = red[0][c1] + red[1][c1] + red[2][c1] + red[3][c1];
    atomicAdd(&pooled[g * HD + c0], m0);
    atomicAdd(&pooled[g * HD + c1], m1);
  }
}

// ---------------- MLP head: one wave per graph (4 graphs per block) ----------------
__global__ __launch_bounds__(256)
void k_head(const float* __restrict__ pooled, const int* __restrict__ batch, int n,
            int G, const float* __restrict__ lw1, const float* __restrict__ lb1,
            const float* __restrict__ lw2, const float* __restrict__ lb2,
            float* __restrict__ out) {
  const int g = blockIdx.x * 4 + (threadIdx.x >> 6);
  const int lane = threadIdx.x & 63;
  if (g >= G) return;
  int lo = 0, hi = n;
  while (lo < hi) { int mid = (lo + hi) >> 1; if (batch[mid] < g) lo = mid + 1; else hi = mid; }
  const int start = lo;
  hi = n;
  while (lo < hi) { int mid = (lo + hi) >> 1; if (batch[mid] < g + 1) lo = mid + 1; else hi = mid; }
  const int cnt = lo - start;
  const float invc = (cnt > 0) ? 1.f / (float)cnt : 0.f;
  const int c0 = (lane >> 4) * 32 + (lane & 15), c1 = c0 + 16;
  const float m0 = pooled[g * HD + c0] * invc;
  const float m1 = pooled[g * HD + c1] * invc;
  float t0 = lb1[c0], t1 = lb1[c1];
  for (int k = 0; k < HD; ++k) {
    const int srcl = ((k >> 5) << 4) + (k & 15);
    const float pv = __shfl(((k >> 4) & 1) ? m1 : m0, srcl, 64);
    t0 = fmaf(pv, lw1[k * HD + c0], t0);
    t1 = fmaf(pv, lw1[k * HD + c1], t1);
  }
  t0 = fmaxf(t0, 0.f);
  t1 = fmaxf(t1, 0.f);
  float p = t0 * lw2[c0] + t1 * lw2[c1];
#pragma unroll
  for (int off = 32; off; off >>= 1) p += __shfl_xor(p, off, 64);
  if (lane == 0) out[g] = p + lb2[0];
}

// ---------------- launch ----------------

extern "C" void kernel_launch(void* const* d_in, const int* in_sizes, int n_in,
                              void* d_out, int out_size, void* d_ws, size_t ws_size,
                              hipStream_t stream) {
  const float* x = (const float*)d_in[0];
  const int* ei = (const int*)d_in[1];
  const int* batch = (const int*)d_in[2];
  const float* W1 = (const float*)d_in[3];
  const float* as1 = (const float*)d_in[4];
  const float* ad1 = (const float*)d_in[5];
  const float* b1 = (const float*)d_in[6];
  const float* W2 = (const float*)d_in[7];
  const float* as2 = (const float*)d_in[8];
  const float* ad2 = (const float*)d_in[9];
  const float* b2 = (const float*)d_in[10];
  const float* W3 = (const float*)d_in[11];
  const float* as3 = (const float*)d_in[12];
  const float* ad3 = (const float*)d_in[13];
  const float* b3 = (const float*)d_in[14];
  const float* g1 = (const float*)d_in[15];
  const float* be1 = (const float*)d_in[16];
  const float* m1 = (const float*)d_in[17];
  const float* v1 = (const float*)d_in[18];
  const float* g2 = (const float*)d_in[19];
  const float* be2 = (const float*)d_in[20];
  const float* m2 = (const float*)d_in[21];
  const float* v2 = (const float*)d_in[22];
  const float* g3 = (const float*)d_in[23];
  const float* be3 = (const float*)d_in[24];
  const float* m3 = (const float*)d_in[25];
  const float* v3 = (const float*)d_in[26];
  const float* lw1 = (const float*)d_in[27];
  const float* lb1 = (const float*)d_in[28];
  const float* lw2 = (const float*)d_in[29];
  const float* lb2 = (const float*)d_in[30];

  const int n = in_sizes[0] / 64;  // 50000
  const int E = in_sizes[1] / 2;   // 640000
  const int G = out_size;          // 256 graphs
  const int* src = ei;
  const int* dst = ei + E;

  // workspace carve (4B units)
  uint32* hbuf = (uint32*)d_ws;        // n*64 (bf16x2 packed h)
  uint32* ybuf = hbuf + (long)n * 64;  // n*64 (bf16x2 packed y)
  float* ssrc = (float*)(ybuf + (long)n * 64);  // n
  float* sdstv = ssrc + n;             // n
  int* deg = (int*)(sdstv + n);        // n
  int2* offs2 = (int2*)(deg + n);      // n int2
  int* cursor = (int*)(offs2 + n);     // n
  int* csr = cursor + n;               // E+n
  int* gcnt = csr + (E + n);           // 1 (+pad)
  uint32* PW1 = (uint32*)(gcnt + 4);   // 4096
  uint32* PW2 = PW1 + 4096;            // 8192
  uint32* PW3 = PW2 + 8192;            // 8192
  uint32* BFA1 = PW3 + 8192;           // 512
  uint32* BFA2 = BFA1 + 512;           // 1024
  uint32* BFA3 = BFA2 + 1024;          // 1024
  float4* BNAB = (float4*)(BFA3 + 1024);  // 3*64 float4
  float* pooled = (float*)(BNAB + 3 * 64);  // G*HD floats

  const int B = 256;
  dim3 blk(B);
  const int nb = (n + B - 1) / B;
  const int eb = (E + B - 1) / B;
  const int zb = (n + G * HD + B - 1) / B;  // zero deg + pooled
  const int GB = (n + 63) / 64;

  // 1: pack (PW + score fragments + BN fold) + zero deg/pooled/gcnt
  k_pack<<<dim3(83 + zb), blk, 0, stream>>>(
      W1, as1, ad1, W2, as2, ad2, W3, as3, ad3,
      b1, g1, be1, m1, v1, b2, g2, be2, m2, v2, b3, g3, be3, m3, v3,
      PW1, PW2, PW3, BFA1, BFA2, BFA3, BNAB, deg, gcnt, pooled, G, n);
  // 2: layer-1 gemm (fp32 in) || edge histogram
  k_gemm1_hist<<<dim3(GB + eb), blk, 0, stream>>>(x, PW1, BFA1, hbuf, ssrc, sdstv, n,
                                                  dst, deg, E, GB);
  // 3: CSR segment allocation (scan-free)
  k_alloc<<<dim3(nb), blk, 0, stream>>>(deg, gcnt, offs2, csr, cursor, n);
  // 4: CSR edge fill
  k_fill_edges<<<dim3(eb), blk, 0, stream>>>(src, dst, cursor, csr, E);

  const dim3 agrid((n + 3) / 4);
  // 5: agg layer 1
  k_agg<<<agrid, blk, 0, stream>>>(hbuf, ssrc, sdstv, offs2, csr, BNAB + 0, ybuf, n);
  // 6-7: layer 2
  k_gemm_mfma<128><<<dim3(GB), blk, 0, stream>>>(ybuf, PW2, BFA2, hbuf, ssrc, sdstv, n);
  k_agg<<<agrid, blk, 0, stream>>>(hbuf, ssrc, sdstv, offs2, csr, BNAB + 64, ybuf, n);
  // 8-9: layer 3
  k_gemm_mfma<128><<<dim3(GB), blk, 0, stream>>>(ybuf, PW3, BFA3, hbuf, ssrc, sdstv, n);
  k_agg<<<agrid, blk, 0, stream>>>(hbuf, ssrc, sdstv, offs2, csr, BNAB + 128, ybuf, n);
  // 10: pool partials (4 blocks/graph), 11: head
  k_pool_part<<<dim3(4 * G), blk, 0, stream>>>(ybuf, batch, n, pooled);
  k_head<<<dim3((G + 3) / 4), blk, 0, stream>>>(pooled, batch, n, G, lw1, lb1, lw2,
                                                lb2, (float*)d_out);
}